// Round 7
// baseline (175.044 us; speedup 1.0000x reference)
//
#include <hip/hip_runtime.h>

#define C 32
#define NT 256
#define BSH 8              // 256 nodes per bucket
#define BNODE 256
#define CAPC 5632          // per-bucket capacity (mean 4096, +24 sigma)
#define SRCMASK 0x1FFFF

typedef float f32x4 __attribute__((ext_vector_type(4)));   // nt-builtin-compatible

__device__ __forceinline__ unsigned int f2bf(float f) {
    unsigned int u = __float_as_uint(f);
    return (u + 0x7FFFu + ((u >> 16) & 1u)) >> 16;   // RNE to bf16
}
__device__ __forceinline__ float bflo(unsigned int u) { return __uint_as_float(u << 16); }
__device__ __forceinline__ float bfhi(unsigned int u) { return __uint_as_float(u & 0xFFFF0000u); }

__global__ void init_cursor(int* __restrict__ cursor, int nbuck) {
    int i = blockIdx.x * blockDim.x + threadIdx.x;
    if (i < nbuck) cursor[i] = i * CAPC;
}

// Phase A: bucketize by dst>>8 via per-block LDS hist + one global reservation
// atomic per bucket.
__global__ __launch_bounds__(1024) void phaseA(const int* __restrict__ src,
                                               const int* __restrict__ dst,
                                               int* __restrict__ cursor,
                                               int* __restrict__ pk,
                                               int E, int nbuck, int chunk) {
    extern __shared__ int l[];          // lcnt[nbuck] | lcur[nbuck]
    int* lcnt = l;
    int* lcur = l + nbuck;
    int tid = threadIdx.x;
    for (int i = tid; i < nbuck; i += 1024) lcnt[i] = 0;
    __syncthreads();
    int base = blockIdx.x * chunk;
    int end  = min(base + chunk, E);
    for (int e = base + tid; e < end; e += 1024)
        atomicAdd(&lcnt[dst[e] >> BSH], 1);
    __syncthreads();
    for (int i = tid; i < nbuck; i += 1024) {
        int c = lcnt[i];
        lcur[i] = c ? atomicAdd(&cursor[i], c) : 0;
    }
    __syncthreads();
    for (int e = base + tid; e < end; e += 1024) {
        int d = dst[e];
        int b = d >> BSH;
        int pos = atomicAdd(&lcur[b], 1);
        pk[pos] = src[e] | ((d & (BNODE - 1)) << 17);
    }
}

// Phase B: per-bucket counting sort in place + fused x->bf16 conversion for
// this bucket's 256 contiguous rows.
__global__ __launch_bounds__(512) void phaseB(int* __restrict__ pk,
                                              const int* __restrict__ cursor,
                                              int* __restrict__ row_start,
                                              int* __restrict__ ideg,
                                              const float* __restrict__ x,
                                              uint2* __restrict__ xb2, int N) {
    __shared__ int ent[CAPC];
    __shared__ int h[BNODE];
    __shared__ int s[BNODE];
    __shared__ int cur[BNODE];
    int b = blockIdx.x;
    int tid = threadIdx.x;

    // fused cvt: bucket's own x rows -> packed bf16 (8 x uint2 per row)
    int n0 = b << BSH;
    int nvalid = min(N - n0, BNODE);
    for (int i = tid; i < nvalid * 8; i += 512) {
        int n = n0 + (i >> 3);
        int lq = i & 7;
        const float* xp = x + (size_t)n * C + lq * 4;
        uint2 r;
        r.x = f2bf(xp[0]) | (f2bf(xp[1]) << 16);
        r.y = f2bf(xp[2]) | (f2bf(xp[3]) << 16);
        xb2[(size_t)n * 8 + lq] = r;
    }

    int base = b * CAPC;
    int cnt = min(cursor[b] - base, CAPC);
    for (int i = tid; i < cnt; i += 512) ent[i] = pk[base + i];
    if (tid < BNODE) h[tid] = 0;
    __syncthreads();
    for (int i = tid; i < cnt; i += 512) atomicAdd(&h[ent[i] >> 17], 1);
    __syncthreads();
    int v = 0;
    if (tid < BNODE) { v = h[tid]; s[tid] = v; }
    __syncthreads();
    for (int off = 1; off < BNODE; off <<= 1) {
        int u = 0;
        if (tid < BNODE && tid >= off) u = s[tid - off];
        __syncthreads();
        if (tid < BNODE) s[tid] += u;
        __syncthreads();
    }
    if (tid < BNODE) {
        int exc = s[tid] - v;
        int n = n0 + tid;
        if (n < N) { row_start[n] = base + exc; ideg[n] = v; }
        cur[tid] = exc;
    }
    __syncthreads();
    for (int i = tid; i < cnt; i += 512) {
        int en = ent[i];
        int pos = atomicAdd(&cur[en >> 17], 1);
        pk[base + pos] = en & SRCMASK;
    }
}

// ---- gathers: 8 lanes/node, uint2 (4 bf16 ch) per lane, 8-deep unroll ----
// Per wave: 8 nodes x 8 rows = 64 independent 64B lines in flight.
#define ACC4(u0, u1)                                     \
    a0 += bflo(u0); a1 += bfhi(u0);                      \
    a2 += bflo(u1); a3 += bfhi(u1);

__global__ __launch_bounds__(NT) void gather1_bf(const float* __restrict__ x,
        const uint2* __restrict__ xb2, const int* __restrict__ pk,
        const int* __restrict__ row_start, const int* __restrict__ ideg,
        float* __restrict__ t1, uint2* __restrict__ t1b2, int N) {
    int g = blockIdx.x * blockDim.x + threadIdx.x;
    int n = g >> 3;
    if (n >= N) return;
    int lq = g & 7;
    int rs = row_start[n];
    int dg = ideg[n];
    int re = rs + dg;
    float a0 = 0.f, a1 = 0.f, a2 = 0.f, a3 = 0.f;
    int j = rs;
    for (; j + 7 < re; j += 8) {
        int s0 = __builtin_nontemporal_load(&pk[j]);
        int s1 = __builtin_nontemporal_load(&pk[j + 1]);
        int s2 = __builtin_nontemporal_load(&pk[j + 2]);
        int s3 = __builtin_nontemporal_load(&pk[j + 3]);
        int s4 = __builtin_nontemporal_load(&pk[j + 4]);
        int s5 = __builtin_nontemporal_load(&pk[j + 5]);
        int s6 = __builtin_nontemporal_load(&pk[j + 6]);
        int s7 = __builtin_nontemporal_load(&pk[j + 7]);
        uint2 u0 = xb2[(size_t)s0 * 8 + lq];
        uint2 u1 = xb2[(size_t)s1 * 8 + lq];
        uint2 u2 = xb2[(size_t)s2 * 8 + lq];
        uint2 u3 = xb2[(size_t)s3 * 8 + lq];
        uint2 u4 = xb2[(size_t)s4 * 8 + lq];
        uint2 u5 = xb2[(size_t)s5 * 8 + lq];
        uint2 u6 = xb2[(size_t)s6 * 8 + lq];
        uint2 u7 = xb2[(size_t)s7 * 8 + lq];
        ACC4(u0.x, u0.y) ACC4(u1.x, u1.y) ACC4(u2.x, u2.y) ACC4(u3.x, u3.y)
        ACC4(u4.x, u4.y) ACC4(u5.x, u5.y) ACC4(u6.x, u6.y) ACC4(u7.x, u7.y)
    }
    for (; j + 1 < re; j += 2) {
        int s0 = __builtin_nontemporal_load(&pk[j]);
        int s1 = __builtin_nontemporal_load(&pk[j + 1]);
        uint2 u0 = xb2[(size_t)s0 * 8 + lq];
        uint2 u1 = xb2[(size_t)s1 * 8 + lq];
        ACC4(u0.x, u0.y) ACC4(u1.x, u1.y)
    }
    if (j < re) {
        uint2 u0 = xb2[(size_t)__builtin_nontemporal_load(&pk[j]) * 8 + lq];
        ACC4(u0.x, u0.y)
    }
    size_t o = (size_t)n * C + lq * 4;
    f32x4 xv = __builtin_nontemporal_load((const f32x4*)(x + o));
    float fdg = (float)dg;
    f32x4 tv;
    tv.x = fdg * xv.x - a0;
    tv.y = fdg * xv.y - a1;
    tv.z = fdg * xv.z - a2;
    tv.w = fdg * xv.w - a3;
    __builtin_nontemporal_store(tv, (f32x4*)(t1 + o));
    uint2 r;
    r.x = f2bf(tv.x) | (f2bf(tv.y) << 16);
    r.y = f2bf(tv.z) | (f2bf(tv.w) << 16);
    t1b2[(size_t)n * 8 + lq] = r;
}

__global__ __launch_bounds__(NT) void gather2_bf(const float* __restrict__ x,
        const float* __restrict__ t1, const uint2* __restrict__ t1b2,
        const int* __restrict__ pk, const int* __restrict__ row_start,
        const int* __restrict__ ideg, const float* __restrict__ wts,
        float* __restrict__ y, int N) {
    int g = blockIdx.x * blockDim.x + threadIdx.x;
    int n = g >> 3;
    if (n >= N) return;
    int lq = g & 7;
    int rs = row_start[n];
    int dg = ideg[n];
    int re = rs + dg;
    float a0 = 0.f, a1 = 0.f, a2 = 0.f, a3 = 0.f;
    int j = rs;
    for (; j + 7 < re; j += 8) {
        int s0 = __builtin_nontemporal_load(&pk[j]);
        int s1 = __builtin_nontemporal_load(&pk[j + 1]);
        int s2 = __builtin_nontemporal_load(&pk[j + 2]);
        int s3 = __builtin_nontemporal_load(&pk[j + 3]);
        int s4 = __builtin_nontemporal_load(&pk[j + 4]);
        int s5 = __builtin_nontemporal_load(&pk[j + 5]);
        int s6 = __builtin_nontemporal_load(&pk[j + 6]);
        int s7 = __builtin_nontemporal_load(&pk[j + 7]);
        uint2 u0 = t1b2[(size_t)s0 * 8 + lq];
        uint2 u1 = t1b2[(size_t)s1 * 8 + lq];
        uint2 u2 = t1b2[(size_t)s2 * 8 + lq];
        uint2 u3 = t1b2[(size_t)s3 * 8 + lq];
        uint2 u4 = t1b2[(size_t)s4 * 8 + lq];
        uint2 u5 = t1b2[(size_t)s5 * 8 + lq];
        uint2 u6 = t1b2[(size_t)s6 * 8 + lq];
        uint2 u7 = t1b2[(size_t)s7 * 8 + lq];
        ACC4(u0.x, u0.y) ACC4(u1.x, u1.y) ACC4(u2.x, u2.y) ACC4(u3.x, u3.y)
        ACC4(u4.x, u4.y) ACC4(u5.x, u5.y) ACC4(u6.x, u6.y) ACC4(u7.x, u7.y)
    }
    for (; j + 1 < re; j += 2) {
        int s0 = __builtin_nontemporal_load(&pk[j]);
        int s1 = __builtin_nontemporal_load(&pk[j + 1]);
        uint2 u0 = t1b2[(size_t)s0 * 8 + lq];
        uint2 u1 = t1b2[(size_t)s1 * 8 + lq];
        ACC4(u0.x, u0.y) ACC4(u1.x, u1.y)
    }
    if (j < re) {
        uint2 u0 = t1b2[(size_t)__builtin_nontemporal_load(&pk[j]) * 8 + lq];
        ACC4(u0.x, u0.y)
    }
    size_t o = (size_t)n * C + lq * 4;
    f32x4 xv = __builtin_nontemporal_load((const f32x4*)(x + o));
    f32x4 tv = __builtin_nontemporal_load((const f32x4*)(t1 + o));
    float w0 = wts[0], w1 = wts[1], w2 = wts[2];
    float fdg = (float)dg;
    f32x4 r;
    r.x = w0 * xv.x + w1 * tv.x + w2 * (fdg * tv.x - a0);
    r.y = w0 * xv.y + w1 * tv.y + w2 * (fdg * tv.y - a1);
    r.z = w0 * xv.z + w1 * tv.z + w2 * (fdg * tv.z - a2);
    r.w = w0 * xv.w + w1 * tv.w + w2 * (fdg * tv.w - a3);
    __builtin_nontemporal_store(r, (f32x4*)(y + o));
}

// ---- fp32 fallback gathers (R4-proven) used only if ws_size is too small ----
__global__ __launch_bounds__(NT) void gather1_f32(const float* __restrict__ x,
        const int* __restrict__ pk, const int* __restrict__ row_start,
        const int* __restrict__ ideg, float* __restrict__ t1, int N) {
    int g = blockIdx.x * blockDim.x + threadIdx.x;
    int n = g >> 5;
    if (n >= N) return;
    int ch = g & 31;
    int rs = row_start[n], dg = ideg[n], re = rs + dg;
    float a0 = 0, a1 = 0, a2 = 0, a3 = 0;
    int j = rs;
    for (; j + 3 < re; j += 4) {
        a0 += x[(size_t)pk[j] * C + ch];     a1 += x[(size_t)pk[j + 1] * C + ch];
        a2 += x[(size_t)pk[j + 2] * C + ch]; a3 += x[(size_t)pk[j + 3] * C + ch];
    }
    for (; j < re; ++j) a0 += x[(size_t)pk[j] * C + ch];
    size_t o = (size_t)n * C + ch;
    t1[o] = (float)dg * x[o] - ((a0 + a1) + (a2 + a3));
}
__global__ __launch_bounds__(NT) void gather2_f32(const float* __restrict__ x,
        const float* __restrict__ t1, const int* __restrict__ pk,
        const int* __restrict__ row_start, const int* __restrict__ ideg,
        const float* __restrict__ wts, float* __restrict__ y, int N) {
    int g = blockIdx.x * blockDim.x + threadIdx.x;
    int n = g >> 5;
    if (n >= N) return;
    int ch = g & 31;
    int rs = row_start[n], dg = ideg[n], re = rs + dg;
    float a0 = 0, a1 = 0, a2 = 0, a3 = 0;
    int j = rs;
    for (; j + 3 < re; j += 4) {
        a0 += t1[(size_t)pk[j] * C + ch];     a1 += t1[(size_t)pk[j + 1] * C + ch];
        a2 += t1[(size_t)pk[j + 2] * C + ch]; a3 += t1[(size_t)pk[j + 3] * C + ch];
    }
    for (; j < re; ++j) a0 += t1[(size_t)pk[j] * C + ch];
    size_t o = (size_t)n * C + ch;
    float tv = t1[o];
    y[o] = wts[0] * x[o] + wts[1] * tv + wts[2] * ((float)dg * tv - ((a0 + a1) + (a2 + a3)));
}

extern "C" void kernel_launch(void* const* d_in, const int* in_sizes, int n_in,
                              void* d_out, int out_size, void* d_ws, size_t ws_size,
                              hipStream_t stream) {
    const float* x    = (const float*)d_in[0];
    const float* wts  = (const float*)d_in[1];
    const int*   esrc = (const int*)d_in[2];
    const int*   edst = (const int*)d_in[3];
    float*       y    = (float*)d_out;

    const int N = in_sizes[0] / C;                 // 100000
    const int E = in_sizes[2];                     // 1600000
    const int nbuck = (N + BNODE - 1) >> BSH;      // 391
    const int nc = N * C;

    char* p = (char*)d_ws;
    auto align16 = [](size_t s) { return (s + 15) & ~(size_t)15; };
    int* cursor    = (int*)p; p += align16((size_t)nbuck * 4);
    int* row_start = (int*)p; p += align16((size_t)N * 4);
    int* ideg      = (int*)p; p += align16((size_t)N * 4);
    int* pk        = (int*)p; p += align16((size_t)nbuck * CAPC * 4);
    float* t1      = (float*)p; p += align16((size_t)nc * 4);
    uint2* xb2     = (uint2*)p; p += align16((size_t)nc * 2);
    uint2* t1b2    = (uint2*)p; p += align16((size_t)nc * 2);
    bool bf_ok = (size_t)(p - (char*)d_ws) <= ws_size;

    init_cursor<<<(nbuck + NT - 1) / NT, NT, 0, stream>>>(cursor, nbuck);

    const int ABLK = 256;
    const int chunk = (E + ABLK - 1) / ABLK;
    const size_t lds_a = (size_t)nbuck * 2 * 4;
    phaseA<<<ABLK, 1024, lds_a, stream>>>(esrc, edst, cursor, pk, E, nbuck, chunk);
    phaseB<<<nbuck, 512, 0, stream>>>(pk, cursor, row_start, ideg, x, xb2, N);

    if (bf_ok) {
        const int gblocks = ((size_t)N * 8 + NT - 1) / NT;
        gather1_bf<<<gblocks, NT, 0, stream>>>(x, xb2, pk, row_start, ideg, t1, t1b2, N);
        gather2_bf<<<gblocks, NT, 0, stream>>>(x, t1, t1b2, pk, row_start, ideg, wts, y, N);
    } else {
        const int gblocks = ((size_t)N * 32 + NT - 1) / NT;
        gather1_f32<<<gblocks, NT, 0, stream>>>(x, pk, row_start, ideg, t1, N);
        gather2_f32<<<gblocks, NT, 0, stream>>>(x, t1, pk, row_start, ideg, wts, y, N);
    }
}